// Round 19
// baseline (50.485 us; speedup 1.0000x reference)
//
#include <hip/hip_runtime.h>
#include <cmath>

#define FDIM 128
#define NPTS 64            /* table points over d in [0, 10.24) */
#define TDLT 0.16f
#define INVTDLT 6.25f
#define CLAMPF 62.0f       /* max fidx -> idx<=62, reads row idx+1<=63 */

typedef __attribute__((ext_vector_type(8))) __bf16 bf16x8;
typedef __attribute__((ext_vector_type(4))) float f32x4;

// RNE f32 -> bf16 bits
__device__ inline unsigned short f2bf(float x) {
  unsigned int u = __float_as_uint(x);
  return (unsigned short)((u + 0x7FFFu + ((u >> 16) & 1u)) >> 16);
}
__device__ inline float bfw_lo(unsigned int w) { return __uint_as_float(w << 16); }
__device__ inline float bfw_hi(unsigned int w) { return __uint_as_float(w & 0xFFFF0000u); }
__device__ inline float rdlane(float v, int j) {
  return __int_as_float(__builtin_amdgcn_readlane(__float_as_int(v), j));
}

// ---------------------------------------------------------------------------
// One-time weight fragment pack (bf16 MFMA B-frag layout [ft][kt][lane][j]).
__global__ __launch_bounds__(64) void pack_frag_kernel(
    const float* __restrict__ W1, const float* __restrict__ W2,
    unsigned short* __restrict__ W1f, unsigned short* __restrict__ W2f) {
  const int ft = blockIdx.x, kt = blockIdx.y, z = blockIdx.z;
  const int lane = threadIdx.x;
  const float* W;
  unsigned short* out;
  int col, stride;
  if (z == 0) {
    if (ft >= 8) return;
    W = W1; out = W1f; col = ft * 16 + (lane & 15); stride = 128;
  } else {
    W = W2; out = W2f;
    col = 3 * ((ft & 7) * 16 + (lane & 15)) + 1 + (ft >> 3);
    stride = 384;
  }
  unsigned short g[8];
#pragma unroll
  for (int j = 0; j < 8; ++j) {
    const int k = kt * 32 + ((lane >> 4) << 3) + j;
    g[j] = f2bf(W[(size_t)k * stride + col]);
  }
  uint4 u;
  u.x = g[0] | ((unsigned int)g[1] << 16);
  u.y = g[2] | ((unsigned int)g[3] << 16);
  u.z = g[4] | ((unsigned int)g[5] << 16);
  u.w = g[6] | ((unsigned int)g[7] << 16);
  *(uint4*)&out[((size_t)(ft * 4 + kt) * 64 + lane) * 8] = u;
}

// ---------------------------------------------------------------------------
// Table, transposed layout: Tq[pt][l] (uint2).
__global__ __launch_bounds__(256) void build_table_kernel(
    const float* __restrict__ Wf, const float* __restrict__ bf,
    unsigned int* __restrict__ Tq) {
  __shared__ float g[128];
  __shared__ float part[2][128][2];
  const int pt = blockIdx.x;
  const int tid = threadIdx.x;
  const int f = tid & 127;
  const int kh = tid >> 7;
  if (tid < 128) {
    const float dpt = pt * TDLT;
    const float o = tid * (5.0f / 127.0f);
    const float dd = dpt - o;
    g[tid] = expf(-dd * dd);
  }
  __syncthreads();
  float s0 = 0.f, s1 = 0.f;
#pragma unroll 8
  for (int kk = 0; kk < 64; ++kk) {
    const int k = kh * 64 + kk;
    s0 = fmaf(g[k], Wf[(size_t)k * 384 + 3 * f + 1], s0);
    s1 = fmaf(g[k], Wf[(size_t)k * 384 + 3 * f + 2], s1);
  }
  part[kh][f][0] = s0;
  part[kh][f][1] = s1;
  __syncthreads();
  if (tid < 128) {
    const float v0 = part[0][tid][0] + part[1][tid][0] + bf[3 * tid + 1];
    const float v1 = part[0][tid][1] + part[1][tid][1] + bf[3 * tid + 2];
    const unsigned int word = f2bf(v0) | ((unsigned int)f2bf(v1) << 16);
    Tq[((size_t)pt * 64 + (tid & 63)) * 2 + (tid >> 6)] = word;
  }
}

// ---------------------------------------------------------------------------
// phi = silu(h@W1+b1)@W2+b2 (used cols only), two MFMA passes, 16 rows/block.
__global__ __launch_bounds__(256) void phi_mfma_kernel(
    const float* __restrict__ h, const unsigned short* __restrict__ W1f,
    const float* __restrict__ b1, const unsigned short* __restrict__ W2f,
    const float* __restrict__ b2, unsigned int* __restrict__ phiQ, int BNA) {
  __shared__ __bf16 hA[4 * 64 * 8];           // 4 KB: h tile (16 rows), A-frag layout
  __shared__ unsigned short tS[16 * 128];     // 4 KB: t tile, swizzled row-major
  const int tid = threadIdx.x;
  const int lane = tid & 63;
  const int w = tid >> 6;       // 0..3
  const int hw = lane >> 4, lcol = lane & 15;
  const int r0 = blockIdx.x * 16;

  {
    const int gl = tid & 63;
    const int kt = tid >> 6;
    const int row = gl & 15;
    const int k0 = kt * 32 + ((gl >> 4) << 3);
    const int gr = r0 + row;
    bf16x8 v;
    if (gr < BNA) {
      const float4 f0 = *(const float4*)&h[(size_t)gr * FDIM + k0];
      const float4 f1 = *(const float4*)&h[(size_t)gr * FDIM + k0 + 4];
      v[0] = (__bf16)f0.x; v[1] = (__bf16)f0.y; v[2] = (__bf16)f0.z; v[3] = (__bf16)f0.w;
      v[4] = (__bf16)f1.x; v[5] = (__bf16)f1.y; v[6] = (__bf16)f1.z; v[7] = (__bf16)f1.w;
    } else {
#pragma unroll
      for (int j = 0; j < 8; ++j) v[j] = (__bf16)0.0f;
    }
    *reinterpret_cast<bf16x8*>(&hA[tid * 8]) = v;
  }

  bf16x8 B1[2][4];
#pragma unroll
  for (int ftl = 0; ftl < 2; ++ftl)
#pragma unroll
    for (int kt = 0; kt < 4; ++kt)
      B1[ftl][kt] = *reinterpret_cast<const bf16x8*>(
          &W1f[(((size_t)(w * 2 + ftl) * 4 + kt) * 64 + lane) * 8]);
  float b1v[2];
#pragma unroll
  for (int ftl = 0; ftl < 2; ++ftl) b1v[ftl] = b1[w * 32 + ftl * 16 + lcol];
  __syncthreads();

  {
    bf16x8 ga[4];
#pragma unroll
    for (int kt = 0; kt < 4; ++kt)
      ga[kt] = *reinterpret_cast<const bf16x8*>(&hA[(kt * 64 + lane) * 8]);
    f32x4 acc[2];
    acc[0] = (f32x4){0.f, 0.f, 0.f, 0.f};
    acc[1] = (f32x4){0.f, 0.f, 0.f, 0.f};
#pragma unroll
    for (int ftl = 0; ftl < 2; ++ftl)
#pragma unroll
      for (int kt = 0; kt < 4; ++kt)
        acc[ftl] = __builtin_amdgcn_mfma_f32_16x16x32_bf16(ga[kt], B1[ftl][kt], acc[ftl], 0, 0, 0);
#pragma unroll
    for (int ftl = 0; ftl < 2; ++ftl)
#pragma unroll
      for (int reg = 0; reg < 4; ++reg) {
        const int row = hw * 4 + reg;
        const int fcol = w * 32 + ftl * 16 + lcol;
        const float x = acc[ftl][reg] + b1v[ftl];
        const float t = x / (1.0f + __expf(-x));
        const int byte = (row * 256 + fcol * 2) ^ ((row & 7) << 4);
        *(unsigned short*)((char*)tS + byte) = f2bf(t);
      }
  }

  bf16x8 B2[2][2][4];  // [ftl][s][kt]
  float b2v[2][2];
#pragma unroll
  for (int ftl = 0; ftl < 2; ++ftl) {
    const int fcol = w * 32 + ftl * 16 + lcol;
#pragma unroll
    for (int s_ = 0; s_ < 2; ++s_) {
      const int ft = s_ * 8 + w * 2 + ftl;
#pragma unroll
      for (int kt = 0; kt < 4; ++kt)
        B2[ftl][s_][kt] = *reinterpret_cast<const bf16x8*>(
            &W2f[(((size_t)ft * 4 + kt) * 64 + lane) * 8]);
      b2v[ftl][s_] = b2[3 * fcol + 1 + s_];
    }
  }
  __syncthreads();

  {
    bf16x8 ta[4];
#pragma unroll
    for (int kt = 0; kt < 4; ++kt) {
      const int row = lcol;
      const int k0 = kt * 32 + hw * 8;
      const int byte = (row * 256 + k0 * 2) ^ ((row & 7) << 4);
      ta[kt] = *reinterpret_cast<const bf16x8*>((const char*)tS + byte);
    }
    f32x4 acc[2][2];
#pragma unroll
    for (int ftl = 0; ftl < 2; ++ftl)
#pragma unroll
      for (int s_ = 0; s_ < 2; ++s_) acc[ftl][s_] = (f32x4){0.f, 0.f, 0.f, 0.f};
#pragma unroll
    for (int ftl = 0; ftl < 2; ++ftl)
#pragma unroll
      for (int s_ = 0; s_ < 2; ++s_)
#pragma unroll
        for (int kt = 0; kt < 4; ++kt)
          acc[ftl][s_] = __builtin_amdgcn_mfma_f32_16x16x32_bf16(ta[kt], B2[ftl][s_][kt],
                                                                 acc[ftl][s_], 0, 0, 0);
#pragma unroll
    for (int ftl = 0; ftl < 2; ++ftl)
#pragma unroll
      for (int reg = 0; reg < 4; ++reg) {
        const int row = hw * 4 + reg;
        const int gr = r0 + row;
        if (gr < BNA) {
          const float v0 = acc[ftl][0][reg] + b2v[ftl][0];
          const float v1 = acc[ftl][1][reg] + b2v[ftl][1];
          const unsigned int word = f2bf(v0) | ((unsigned int)f2bf(v1) << 16);
          phiQ[(size_t)gr * FDIM + w * 32 + ftl * 16 + lcol] = word;
        }
      }
  }
}

// ---------------------------------------------------------------------------
// Main kernel — DIAGNOSTIC build: identical to R18 except the atom loop runs
// REPS=2 times (accumulating both, final write x0.5 — exact in fp32, and
// rep-0 work feeds the final value so it cannot be DCE'd). This doubles enc's
// duration so it surfaces in the rocprof top-5 with full counters (VGPR,
// VALUBusy, Occupancy, bank conflicts) for the first time.
template <int ASPLIT>
__global__ __launch_bounds__(256, 4) void enc_main_kernel(
    const float* __restrict__ xyz, const float* __restrict__ cg_xyz,
    const unsigned int* __restrict__ Tg, const unsigned int* __restrict__ phiQ,
    float* __restrict__ pH, float* __restrict__ pV,
    int NA, int NC, int BNC, int BNA) {
  __shared__ uint2 Tl[NPTS * 64];   // 32 KB, [pt][l]
  __shared__ float red[4][64][8];   // 8 KB cross-wave reduction

  const int az = blockIdx.x;
  const int c = blockIdx.y;
  const int b = blockIdx.z;
  const int bc = b * NC + c;
  const int tid = threadIdx.x;
  const int l = tid & 63;
  const int wv = tid >> 6;
  const size_t arow = (size_t)b * NA;

  {
    const uint4* src4 = (const uint4*)Tg;
    uint4* dst4 = (uint4*)Tl;
#pragma unroll
    for (int i = 0; i < 8; ++i) dst4[tid + i * 256] = src4[tid + i * 256];
  }

  const float cgx = cg_xyz[bc * 3 + 0];
  const float cgy = cg_xyz[bc * 3 + 1];
  const float cgz = cg_xyz[bc * 3 + 2];

  const int APA = (NA + ASPLIT - 1) / ASPLIT;
  const int a0 = az * APA;
  const int a_end = min(NA, a0 + APA);
  const int cnt = (a_end > a0) ? (a_end - a0) : 0;
  const int wcnt = (cnt + 3) >> 2;
  const int aw0 = a0 + wv * wcnt;
  const int aw1 = min(a_end, aw0 + wcnt);

  __syncthreads();  // table ready

  float accH0 = 0.f, accH1 = 0.f;
  float accV0[3] = {0.f, 0.f, 0.f};
  float accV1[3] = {0.f, 0.f, 0.f};

  for (int rep = 0; rep < 2; ++rep) {           // DIAGNOSTIC x2 (write x0.5)
  for (int base = aw0; base < aw1; base += 64) {
    int n = aw1 - base;
    if (n > 64) n = 64;

    float fidx = 0.f, ux = 0.f, uy = 0.f, uz = 0.f;
    if (l < n) {
      const int a = base + l;
      const float dx = xyz[(arow + a) * 3 + 0] - cgx;
      const float dy = xyz[(arow + a) * 3 + 1] - cgy;
      const float dz = xyz[(arow + a) * 3 + 2] - cgz;
      const float d = sqrtf(dx * dx + dy * dy + dz * dz);
      const float inv = 1.0f / d;
      ux = dx * inv; uy = dy * inv; uz = dz * inv;
      fidx = fminf(d * INVTDLT, CLAMPF);
    }

    const unsigned int* pq = phiQ + ((size_t)(arow + base)) * FDIM + l;

    for (int jb = 0; jb < n; jb += 4) {
      uint2 t0[4], t1[4];
      float fr[4], sux[4], suy[4], suz[4];
      unsigned int pa[4], pb[4];
#pragma unroll
      for (int q = 0; q < 4; ++q) {
        const int jj = jb + q;
        const int jl = jj & 63;
        const float sf = rdlane(fidx, jl);
        const int idx = (int)sf;
        fr[q] = sf - (float)idx;
        t0[q] = Tl[idx * 64 + l];
        t1[q] = Tl[idx * 64 + 64 + l];
        sux[q] = rdlane(ux, jl);
        suy[q] = rdlane(uy, jl);
        suz[q] = rdlane(uz, jl);
        if (jj < n) {
          pa[q] = pq[(size_t)jj * FDIM];
          pb[q] = pq[(size_t)jj * FDIM + 64];
        } else {
          pa[q] = 0u; pb[q] = 0u;
        }
      }
#pragma unroll
      for (int q = 0; q < 4; ++q) {
        const float A1 = bfw_lo(t0[q].x), A2 = bfw_hi(t0[q].x);
        const float B1 = bfw_lo(t1[q].x), B2 = bfw_hi(t1[q].x);
        const float C1 = bfw_lo(t0[q].y), C2 = bfw_hi(t0[q].y);
        const float D1 = bfw_lo(t1[q].y), D2 = bfw_hi(t1[q].y);
        const float S1a = fmaf(fr[q], B1 - A1, A1);
        const float S2a = fmaf(fr[q], B2 - A2, A2);
        const float S1b = fmaf(fr[q], D1 - C1, C1);
        const float S2b = fmaf(fr[q], D2 - C2, C2);

        const float p1a = bfw_lo(pa[q]), p2a = bfw_hi(pa[q]);
        const float p1b = bfw_lo(pb[q]), p2b = bfw_hi(pb[q]);

        accH0 = fmaf(S1a, p1a, accH0);
        accH1 = fmaf(S1b, p1b, accH1);
        const float t2a = S2a * p2a;
        const float t2b = S2b * p2b;
        accV0[0] = fmaf(t2a, sux[q], accV0[0]);
        accV0[1] = fmaf(t2a, suy[q], accV0[1]);
        accV0[2] = fmaf(t2a, suz[q], accV0[2]);
        accV1[0] = fmaf(t2b, sux[q], accV1[0]);
        accV1[1] = fmaf(t2b, suy[q], accV1[1]);
        accV1[2] = fmaf(t2b, suz[q], accV1[2]);
      }
    }
  }
  }  // rep

  // ---- in-block cross-wave reduction; x0.5 undoes the diagnostic x2 ----
  red[wv][l][0] = accH0 * 0.5f;  red[wv][l][1] = accH1 * 0.5f;
  red[wv][l][2] = accV0[0] * 0.5f; red[wv][l][3] = accV0[1] * 0.5f; red[wv][l][4] = accV0[2] * 0.5f;
  red[wv][l][5] = accV1[0] * 0.5f; red[wv][l][6] = accV1[1] * 0.5f; red[wv][l][7] = accV1[2] * 0.5f;
  __syncthreads();
#pragma unroll
  for (int i = 0; i < 2; ++i) {
    const int slot = tid + i * 256;
    const int sl = slot >> 3;
    const int comp = slot & 7;
    const float v = red[0][sl][comp] + red[1][sl][comp] +
                    red[2][sl][comp] + red[3][sl][comp];
    if (comp == 0) {
      pH[((size_t)az * BNC + bc) * FDIM + sl] = v;
    } else if (comp == 1) {
      pH[((size_t)az * BNC + bc) * FDIM + sl + 64] = v;
    } else if (comp < 5) {
      pV[(((size_t)az * BNC + bc) * FDIM + sl) * 3 + (comp - 2)] = v;
    } else {
      pV[(((size_t)az * BNC + bc) * FDIM + sl + 64) * 3 + (comp - 5)] = v;
    }
  }
}

// ---------------------------------------------------------------------------
template <int P>
__global__ __launch_bounds__(FDIM) void reduce_kernel(
    const float* __restrict__ H, const float* __restrict__ pH, const float* __restrict__ pV,
    float* __restrict__ out, int BNC) {
  const int bc = blockIdx.x;
  const int f = threadIdx.x;
  float s = H[(size_t)bc * FDIM + f];
#pragma unroll
  for (int p = 0; p < P; ++p) s += pH[((size_t)p * BNC + bc) * FDIM + f];
  out[(size_t)bc * FDIM + f] = s;
  float* outV = out + (size_t)BNC * FDIM;
#pragma unroll
  for (int x = 0; x < 3; ++x) {
    float v = 0.f;
#pragma unroll
    for (int p = 0; p < P; ++p) v += pV[(((size_t)p * BNC + bc) * FDIM + f) * 3 + x];
    outV[((size_t)bc * FDIM + f) * 3 + x] = v;
  }
}

extern "C" void kernel_launch(void* const* d_in, const int* in_sizes, int n_in,
                              void* d_out, int out_size, void* d_ws, size_t ws_size,
                              hipStream_t stream) {
  const float* h      = (const float*)d_in[1];
  const float* Hc     = (const float*)d_in[2];
  const float* cg_xyz = (const float*)d_in[3];
  const float* xyz    = (const float*)d_in[4];
  const float* Wf     = (const float*)d_in[6];
  const float* bf     = (const float*)d_in[7];
  const float* W1     = (const float*)d_in[8];
  const float* b1     = (const float*)d_in[9];
  const float* W2     = (const float*)d_in[10];
  const float* b2     = (const float*)d_in[11];

  const int BNC = in_sizes[2] / FDIM;      // B*NC
  const int NC  = in_sizes[5] / BNC;       // cg_adj = B*NC*NC
  const int B   = BNC / NC;
  const int NA  = in_sizes[0] / B;
  const int BNA = B * NA;
  constexpr int ASPLIT = 8;                // P = 8 partials per (bc)

  char* wsb = (char*)d_ws;
  unsigned short* W1f = (unsigned short*)wsb;                       // 32768 B
  unsigned short* W2f = (unsigned short*)(wsb + 32768);             // 65536 B
  unsigned int*  Tq   = (unsigned int*)(wsb + 32768 + 65536);       // 32768 B
  unsigned int*  phiQ = (unsigned int*)(wsb + 2 * 65536);
  char* pp = wsb + 2 * 65536 + (size_t)BNA * FDIM * 4;
  float* pH = (float*)pp;                  pp += (size_t)ASPLIT * BNC * FDIM * 4;
  float* pV = (float*)pp;

  pack_frag_kernel<<<dim3(16, 4, 2), 64, 0, stream>>>(W1, W2, W1f, W2f);
  build_table_kernel<<<NPTS, 256, 0, stream>>>(Wf, bf, Tq);
  phi_mfma_kernel<<<(BNA + 15) / 16, 256, 0, stream>>>(h, W1f, b1, W2f, b2, phiQ, BNA);
  enc_main_kernel<ASPLIT><<<dim3(ASPLIT, NC, B), 256, 0, stream>>>(
      xyz, cg_xyz, Tq, phiQ, pH, pV, NA, NC, BNC, BNA);
  reduce_kernel<ASPLIT><<<BNC, FDIM, 0, stream>>>(Hc, pH, pV, (float*)d_out, BNC);
}

// Round 20
// 33.230 us; speedup vs baseline: 1.5193x; 1.5193x over previous
//
#include <hip/hip_runtime.h>
#include <cmath>

#define FDIM 128
#define NPTS 64            /* table points over d in [0, 10.24) */
#define TDLT 0.16f
#define INVTDLT 6.25f
#define CLAMPF 62.0f       /* max fidx -> idx<=62, reads row idx+1<=63 */

typedef __attribute__((ext_vector_type(8))) __bf16 bf16x8;
typedef __attribute__((ext_vector_type(4))) float f32x4;

// RNE f32 -> bf16 bits
__device__ inline unsigned short f2bf(float x) {
  unsigned int u = __float_as_uint(x);
  return (unsigned short)((u + 0x7FFFu + ((u >> 16) & 1u)) >> 16);
}
__device__ inline float bfw_lo(unsigned int w) { return __uint_as_float(w << 16); }
__device__ inline float bfw_hi(unsigned int w) { return __uint_as_float(w & 0xFFFF0000u); }
__device__ inline float rdlane(float v, int j) {
  return __int_as_float(__builtin_amdgcn_readlane(__float_as_int(v), j));
}

// ---------------------------------------------------------------------------
// Fused prep: blocks 0..127 pack weight frags; blocks 128..191 build table.
// pack: bf16 MFMA B-frag layout [ft][kt][lane][j] (z=0: W1, z=1: W2 used cols).
// table (transposed): Tq[pt][l] (uint2) with S_s(d_pt, f) packed as bf16 pairs.
__global__ __launch_bounds__(256) void prep_kernel(
    const float* __restrict__ W1, const float* __restrict__ W2,
    const float* __restrict__ Wf, const float* __restrict__ bf,
    unsigned short* __restrict__ W1f, unsigned short* __restrict__ W2f,
    unsigned int* __restrict__ Tq) {
  const int bid = blockIdx.x;
  const int tid = threadIdx.x;
  if (bid < 128) {
    // ---- weight fragment pack (threads 0..63 active) ----
    if (tid >= 64) return;
    const int ft = bid & 15, kt = (bid >> 4) & 3, z = bid >> 6;
    const int lane = tid;
    const float* W;
    unsigned short* out;
    int col, stride;
    if (z == 0) {
      if (ft >= 8) return;
      W = W1; out = W1f; col = ft * 16 + (lane & 15); stride = 128;
    } else {
      W = W2; out = W2f;
      col = 3 * ((ft & 7) * 16 + (lane & 15)) + 1 + (ft >> 3);
      stride = 384;
    }
    unsigned short g[8];
#pragma unroll
    for (int j = 0; j < 8; ++j) {
      const int k = kt * 32 + ((lane >> 4) << 3) + j;
      g[j] = f2bf(W[(size_t)k * stride + col]);
    }
    uint4 u;
    u.x = g[0] | ((unsigned int)g[1] << 16);
    u.y = g[2] | ((unsigned int)g[3] << 16);
    u.z = g[4] | ((unsigned int)g[5] << 16);
    u.w = g[6] | ((unsigned int)g[7] << 16);
    *(uint4*)&out[((size_t)(ft * 4 + kt) * 64 + lane) * 8] = u;
  } else {
    // ---- table build (256 threads: f = tid&127, k-half = tid>>7) ----
    __shared__ float g[128];
    __shared__ float part[2][128][2];
    const int pt = bid - 128;
    const int f = tid & 127;
    const int kh = tid >> 7;
    if (tid < 128) {
      const float dpt = pt * TDLT;
      const float o = tid * (5.0f / 127.0f);
      const float dd = dpt - o;
      g[tid] = expf(-dd * dd);
    }
    __syncthreads();
    float s0 = 0.f, s1 = 0.f;
#pragma unroll 8
    for (int kk = 0; kk < 64; ++kk) {
      const int k = kh * 64 + kk;
      s0 = fmaf(g[k], Wf[(size_t)k * 384 + 3 * f + 1], s0);
      s1 = fmaf(g[k], Wf[(size_t)k * 384 + 3 * f + 2], s1);
    }
    part[kh][f][0] = s0;
    part[kh][f][1] = s1;
    __syncthreads();
    if (tid < 128) {
      const float v0 = part[0][tid][0] + part[1][tid][0] + bf[3 * tid + 1];
      const float v1 = part[0][tid][1] + part[1][tid][1] + bf[3 * tid + 2];
      const unsigned int word = f2bf(v0) | ((unsigned int)f2bf(v1) << 16);
      Tq[((size_t)pt * 64 + (tid & 63)) * 2 + (tid >> 6)] = word;
    }
  }
}

// ---------------------------------------------------------------------------
// phi = silu(h@W1+b1)@W2+b2 (used cols only), two MFMA passes, 16 rows/block.
__global__ __launch_bounds__(256) void phi_mfma_kernel(
    const float* __restrict__ h, const unsigned short* __restrict__ W1f,
    const float* __restrict__ b1, const unsigned short* __restrict__ W2f,
    const float* __restrict__ b2, unsigned int* __restrict__ phiQ, int BNA) {
  __shared__ __bf16 hA[4 * 64 * 8];           // 4 KB: h tile (16 rows), A-frag layout
  __shared__ unsigned short tS[16 * 128];     // 4 KB: t tile, swizzled row-major
  const int tid = threadIdx.x;
  const int lane = tid & 63;
  const int w = tid >> 6;       // 0..3
  const int hw = lane >> 4, lcol = lane & 15;
  const int r0 = blockIdx.x * 16;

  {
    const int gl = tid & 63;
    const int kt = tid >> 6;
    const int row = gl & 15;
    const int k0 = kt * 32 + ((gl >> 4) << 3);
    const int gr = r0 + row;
    bf16x8 v;
    if (gr < BNA) {
      const float4 f0 = *(const float4*)&h[(size_t)gr * FDIM + k0];
      const float4 f1 = *(const float4*)&h[(size_t)gr * FDIM + k0 + 4];
      v[0] = (__bf16)f0.x; v[1] = (__bf16)f0.y; v[2] = (__bf16)f0.z; v[3] = (__bf16)f0.w;
      v[4] = (__bf16)f1.x; v[5] = (__bf16)f1.y; v[6] = (__bf16)f1.z; v[7] = (__bf16)f1.w;
    } else {
#pragma unroll
      for (int j = 0; j < 8; ++j) v[j] = (__bf16)0.0f;
    }
    *reinterpret_cast<bf16x8*>(&hA[tid * 8]) = v;
  }

  bf16x8 B1[2][4];
#pragma unroll
  for (int ftl = 0; ftl < 2; ++ftl)
#pragma unroll
    for (int kt = 0; kt < 4; ++kt)
      B1[ftl][kt] = *reinterpret_cast<const bf16x8*>(
          &W1f[(((size_t)(w * 2 + ftl) * 4 + kt) * 64 + lane) * 8]);
  float b1v[2];
#pragma unroll
  for (int ftl = 0; ftl < 2; ++ftl) b1v[ftl] = b1[w * 32 + ftl * 16 + lcol];
  __syncthreads();

  {
    bf16x8 ga[4];
#pragma unroll
    for (int kt = 0; kt < 4; ++kt)
      ga[kt] = *reinterpret_cast<const bf16x8*>(&hA[(kt * 64 + lane) * 8]);
    f32x4 acc[2];
    acc[0] = (f32x4){0.f, 0.f, 0.f, 0.f};
    acc[1] = (f32x4){0.f, 0.f, 0.f, 0.f};
#pragma unroll
    for (int ftl = 0; ftl < 2; ++ftl)
#pragma unroll
      for (int kt = 0; kt < 4; ++kt)
        acc[ftl] = __builtin_amdgcn_mfma_f32_16x16x32_bf16(ga[kt], B1[ftl][kt], acc[ftl], 0, 0, 0);
#pragma unroll
    for (int ftl = 0; ftl < 2; ++ftl)
#pragma unroll
      for (int reg = 0; reg < 4; ++reg) {
        const int row = hw * 4 + reg;
        const int fcol = w * 32 + ftl * 16 + lcol;
        const float x = acc[ftl][reg] + b1v[ftl];
        const float t = x / (1.0f + __expf(-x));
        const int byte = (row * 256 + fcol * 2) ^ ((row & 7) << 4);
        *(unsigned short*)((char*)tS + byte) = f2bf(t);
      }
  }

  bf16x8 B2[2][2][4];  // [ftl][s][kt]
  float b2v[2][2];
#pragma unroll
  for (int ftl = 0; ftl < 2; ++ftl) {
    const int fcol = w * 32 + ftl * 16 + lcol;
#pragma unroll
    for (int s_ = 0; s_ < 2; ++s_) {
      const int ft = s_ * 8 + w * 2 + ftl;
#pragma unroll
      for (int kt = 0; kt < 4; ++kt)
        B2[ftl][s_][kt] = *reinterpret_cast<const bf16x8*>(
            &W2f[(((size_t)ft * 4 + kt) * 64 + lane) * 8]);
      b2v[ftl][s_] = b2[3 * fcol + 1 + s_];
    }
  }
  __syncthreads();

  {
    bf16x8 ta[4];
#pragma unroll
    for (int kt = 0; kt < 4; ++kt) {
      const int row = lcol;
      const int k0 = kt * 32 + hw * 8;
      const int byte = (row * 256 + k0 * 2) ^ ((row & 7) << 4);
      ta[kt] = *reinterpret_cast<const bf16x8*>((const char*)tS + byte);
    }
    f32x4 acc[2][2];
#pragma unroll
    for (int ftl = 0; ftl < 2; ++ftl)
#pragma unroll
      for (int s_ = 0; s_ < 2; ++s_) acc[ftl][s_] = (f32x4){0.f, 0.f, 0.f, 0.f};
#pragma unroll
    for (int ftl = 0; ftl < 2; ++ftl)
#pragma unroll
      for (int s_ = 0; s_ < 2; ++s_)
#pragma unroll
        for (int kt = 0; kt < 4; ++kt)
          acc[ftl][s_] = __builtin_amdgcn_mfma_f32_16x16x32_bf16(ta[kt], B2[ftl][s_][kt],
                                                                 acc[ftl][s_], 0, 0, 0);
#pragma unroll
    for (int ftl = 0; ftl < 2; ++ftl)
#pragma unroll
      for (int reg = 0; reg < 4; ++reg) {
        const int row = hw * 4 + reg;
        const int gr = r0 + row;
        if (gr < BNA) {
          const float v0 = acc[ftl][0][reg] + b2v[ftl][0];
          const float v1 = acc[ftl][1][reg] + b2v[ftl][1];
          const unsigned int word = f2bf(v0) | ((unsigned int)f2bf(v1) << 16);
          phiQ[(size_t)gr * FDIM + w * 32 + ftl * 16 + lcol] = word;
        }
      }
  }
}

// ---------------------------------------------------------------------------
// Main kernel (interp): 512 threads = 8 waves, grid (ASPLIT=4, NC, B).
// Table-only LDS (32 KB) -> up to 4-5 blocks/CU = 24-32 waves/CU of TLP
// (R18 had 16). Each wave covers all 256 outputs (lane l -> f=l, f=l+64,
// both splits) for its private atom chunk; 4 atoms per group with batched
// issue. Cross-wave reduction REUSES the table LDS after a barrier, so each
// block writes ONE partial (P = ASPLIT).
template <int ASPLIT>
__global__ __launch_bounds__(512, 6) void enc_main_kernel(
    const float* __restrict__ xyz, const float* __restrict__ cg_xyz,
    const unsigned int* __restrict__ Tg, const unsigned int* __restrict__ phiQ,
    float* __restrict__ pH, float* __restrict__ pV,
    int NA, int NC, int BNC, int BNA) {
  __shared__ uint2 Tl[NPTS * 64];   // 32 KB, [pt][l]; reused as reduction buf

  const int az = blockIdx.x;
  const int c = blockIdx.y;
  const int b = blockIdx.z;
  const int bc = b * NC + c;
  const int tid = threadIdx.x;
  const int l = tid & 63;
  const int wv = tid >> 6;          // 0..7
  const size_t arow = (size_t)b * NA;

  // load table to LDS (exactly 4 uint4 per thread)
  {
    const uint4* src4 = (const uint4*)Tg;
    uint4* dst4 = (uint4*)Tl;
#pragma unroll
    for (int i = 0; i < 4; ++i) dst4[tid + i * 512] = src4[tid + i * 512];
  }

  const float cgx = cg_xyz[bc * 3 + 0];
  const float cgy = cg_xyz[bc * 3 + 1];
  const float cgz = cg_xyz[bc * 3 + 2];

  // atom chunk for this (az, wave)
  const int APA = (NA + ASPLIT - 1) / ASPLIT;
  const int a0 = az * APA;
  const int a_end = min(NA, a0 + APA);
  const int cnt = (a_end > a0) ? (a_end - a0) : 0;
  const int wcnt = (cnt + 7) >> 3;
  const int aw0 = a0 + wv * wcnt;
  const int aw1 = min(a_end, aw0 + wcnt);

  __syncthreads();  // table ready

  float accH0 = 0.f, accH1 = 0.f;
  float accV0[3] = {0.f, 0.f, 0.f};
  float accV1[3] = {0.f, 0.f, 0.f};

  for (int base = aw0; base < aw1; base += 64) {
    int n = aw1 - base;
    if (n > 64) n = 64;

    // batch phase: lane computes its atom's d-index + unit vector
    float fidx = 0.f, ux = 0.f, uy = 0.f, uz = 0.f;
    if (l < n) {
      const int a = base + l;
      const float dx = xyz[(arow + a) * 3 + 0] - cgx;
      const float dy = xyz[(arow + a) * 3 + 1] - cgy;
      const float dz = xyz[(arow + a) * 3 + 2] - cgz;
      const float d = sqrtf(dx * dx + dy * dy + dz * dz);
      const float inv = 1.0f / d;
      ux = dx * inv; uy = dy * inv; uz = dz * inv;
      fidx = fminf(d * INVTDLT, CLAMPF);
    }

    const unsigned int* pq = phiQ + ((size_t)(arow + base)) * FDIM + l;

    for (int jb = 0; jb < n; jb += 4) {
      // ---- issue stage: 4 atoms' table reads + phi loads together ----
      uint2 t0[4], t1[4];
      float fr[4], sux[4], suy[4], suz[4];
      unsigned int pa[4], pb[4];
#pragma unroll
      for (int q = 0; q < 4; ++q) {
        const int jj = jb + q;               // wave-uniform
        const int jl = jj & 63;
        const float sf = rdlane(fidx, jl);
        const int idx = (int)sf;
        fr[q] = sf - (float)idx;
        t0[q] = Tl[idx * 64 + l];
        t1[q] = Tl[idx * 64 + 64 + l];
        sux[q] = rdlane(ux, jl);
        suy[q] = rdlane(uy, jl);
        suz[q] = rdlane(uz, jl);
        if (jj < n) {
          pa[q] = pq[(size_t)jj * FDIM];
          pb[q] = pq[(size_t)jj * FDIM + 64];
        } else {
          pa[q] = 0u; pb[q] = 0u;            // zero phi -> zero contribution
        }
      }
      // ---- consume stage: 4 atoms ----
#pragma unroll
      for (int q = 0; q < 4; ++q) {
        const float A1 = bfw_lo(t0[q].x), A2 = bfw_hi(t0[q].x);
        const float B1 = bfw_lo(t1[q].x), B2 = bfw_hi(t1[q].x);
        const float C1 = bfw_lo(t0[q].y), C2 = bfw_hi(t0[q].y);
        const float D1 = bfw_lo(t1[q].y), D2 = bfw_hi(t1[q].y);
        const float S1a = fmaf(fr[q], B1 - A1, A1);
        const float S2a = fmaf(fr[q], B2 - A2, A2);
        const float S1b = fmaf(fr[q], D1 - C1, C1);
        const float S2b = fmaf(fr[q], D2 - C2, C2);

        const float p1a = bfw_lo(pa[q]), p2a = bfw_hi(pa[q]);
        const float p1b = bfw_lo(pb[q]), p2b = bfw_hi(pb[q]);

        accH0 = fmaf(S1a, p1a, accH0);
        accH1 = fmaf(S1b, p1b, accH1);
        const float t2a = S2a * p2a;
        const float t2b = S2b * p2b;
        accV0[0] = fmaf(t2a, sux[q], accV0[0]);
        accV0[1] = fmaf(t2a, suy[q], accV0[1]);
        accV0[2] = fmaf(t2a, suz[q], accV0[2]);
        accV1[0] = fmaf(t2b, sux[q], accV1[0]);
        accV1[1] = fmaf(t2b, suy[q], accV1[1]);
        accV1[2] = fmaf(t2b, suz[q], accV1[2]);
      }
    }
  }

  // ---- cross-wave reduction, reusing table LDS (layout red[comp][wv][l]:
  // writes and reads are both 2 lanes/bank = conflict-free) ----
  __syncthreads();  // everyone done reading the table
  float* red = (float*)Tl;
  red[0 * 512 + wv * 64 + l] = accH0;
  red[1 * 512 + wv * 64 + l] = accH1;
  red[2 * 512 + wv * 64 + l] = accV0[0];
  red[3 * 512 + wv * 64 + l] = accV0[1];
  red[4 * 512 + wv * 64 + l] = accV0[2];
  red[5 * 512 + wv * 64 + l] = accV1[0];
  red[6 * 512 + wv * 64 + l] = accV1[1];
  red[7 * 512 + wv * 64 + l] = accV1[2];
  __syncthreads();
  {
    const int comp = tid >> 6;   // 0..7
    const int sl = tid & 63;
    float v = 0.f;
#pragma unroll
    for (int w8 = 0; w8 < 8; ++w8) v += red[comp * 512 + w8 * 64 + sl];
    if (comp == 0) {
      pH[((size_t)az * BNC + bc) * FDIM + sl] = v;
    } else if (comp == 1) {
      pH[((size_t)az * BNC + bc) * FDIM + sl + 64] = v;
    } else if (comp < 5) {
      pV[(((size_t)az * BNC + bc) * FDIM + sl) * 3 + (comp - 2)] = v;
    } else {
      pV[(((size_t)az * BNC + bc) * FDIM + sl + 64) * 3 + (comp - 5)] = v;
    }
  }
}

// ---------------------------------------------------------------------------
template <int P>
__global__ __launch_bounds__(FDIM) void reduce_kernel(
    const float* __restrict__ H, const float* __restrict__ pH, const float* __restrict__ pV,
    float* __restrict__ out, int BNC) {
  const int bc = blockIdx.x;
  const int f = threadIdx.x;
  float s = H[(size_t)bc * FDIM + f];
#pragma unroll
  for (int p = 0; p < P; ++p) s += pH[((size_t)p * BNC + bc) * FDIM + f];
  out[(size_t)bc * FDIM + f] = s;
  float* outV = out + (size_t)BNC * FDIM;
#pragma unroll
  for (int x = 0; x < 3; ++x) {
    float v = 0.f;
#pragma unroll
    for (int p = 0; p < P; ++p) v += pV[(((size_t)p * BNC + bc) * FDIM + f) * 3 + x];
    outV[((size_t)bc * FDIM + f) * 3 + x] = v;
  }
}

extern "C" void kernel_launch(void* const* d_in, const int* in_sizes, int n_in,
                              void* d_out, int out_size, void* d_ws, size_t ws_size,
                              hipStream_t stream) {
  // inputs: 0 assign(unused), 1 h, 2 H, 3 cg_xyz, 4 xyz, 5 cg_adj(unused),
  //         6 Wf, 7 bf, 8 W1, 9 b1, 10 W2, 11 b2
  const float* h      = (const float*)d_in[1];
  const float* Hc     = (const float*)d_in[2];
  const float* cg_xyz = (const float*)d_in[3];
  const float* xyz    = (const float*)d_in[4];
  const float* Wf     = (const float*)d_in[6];
  const float* bf     = (const float*)d_in[7];
  const float* W1     = (const float*)d_in[8];
  const float* b1     = (const float*)d_in[9];
  const float* W2     = (const float*)d_in[10];
  const float* b2     = (const float*)d_in[11];

  const int BNC = in_sizes[2] / FDIM;      // B*NC
  const int NC  = in_sizes[5] / BNC;       // cg_adj = B*NC*NC
  const int B   = BNC / NC;
  const int NA  = in_sizes[0] / B;
  const int BNA = B * NA;
  constexpr int ASPLIT = 4;                // P = 4 partials per (bc)

  // Workspace: W1f (32 KB) + W2f (64 KB) + Tq (32 KB) + phiQ + pH + pV
  char* wsb = (char*)d_ws;
  unsigned short* W1f = (unsigned short*)wsb;                       // 32768 B
  unsigned short* W2f = (unsigned short*)(wsb + 32768);             // 65536 B
  unsigned int*  Tq   = (unsigned int*)(wsb + 32768 + 65536);       // 32768 B
  unsigned int*  phiQ = (unsigned int*)(wsb + 2 * 65536);
  char* pp = wsb + 2 * 65536 + (size_t)BNA * FDIM * 4;
  float* pH = (float*)pp;                  pp += (size_t)ASPLIT * BNC * FDIM * 4;
  float* pV = (float*)pp;

  prep_kernel<<<128 + NPTS, 256, 0, stream>>>(W1, W2, Wf, bf, W1f, W2f, Tq);
  phi_mfma_kernel<<<(BNA + 15) / 16, 256, 0, stream>>>(h, W1f, b1, W2f, b2, phiQ, BNA);
  enc_main_kernel<ASPLIT><<<dim3(ASPLIT, NC, B), 512, 0, stream>>>(
      xyz, cg_xyz, Tq, phiQ, pH, pV, NA, NC, BNC, BNA);
  reduce_kernel<ASPLIT><<<BNC, FDIM, 0, stream>>>(Hc, pH, pV, (float*)d_out, BNC);
}

// Round 21
// 30.372 us; speedup vs baseline: 1.6622x; 1.0941x over previous
//
#include <hip/hip_runtime.h>
#include <cmath>

#define FDIM 128
#define NPTS 64            /* table points over d in [0, 10.24) */
#define TDLT 0.16f
#define INVTDLT 6.25f
#define CLAMPF 62.0f       /* max fidx -> idx<=62, reads row idx+1<=63 */

typedef __attribute__((ext_vector_type(8))) __bf16 bf16x8;
typedef __attribute__((ext_vector_type(4))) float f32x4;

// RNE f32 -> bf16 bits
__device__ inline unsigned short f2bf(float x) {
  unsigned int u = __float_as_uint(x);
  return (unsigned short)((u + 0x7FFFu + ((u >> 16) & 1u)) >> 16);
}
__device__ inline float bfw_lo(unsigned int w) { return __uint_as_float(w << 16); }
__device__ inline float bfw_hi(unsigned int w) { return __uint_as_float(w & 0xFFFF0000u); }
__device__ inline float rdlane(float v, int j) {
  return __int_as_float(__builtin_amdgcn_readlane(__float_as_int(v), j));
}

// ---------------------------------------------------------------------------
// Combo kernel 1: blocks 0..NPTS-1 build the interp table; blocks NPTS.. run
// phi = silu(h@W1+b1)@W2+b2 (used cols, both splits) with INLINE weight
// fragment packing (no dependency on a pack kernel -> one launch, no race).
// Table (transposed): Tq[pt][l] (uint2) = bf16 pairs (S1,S2) for f=l / f=l+64.
// phi output phiQ2: row-interleaved uint2 per (row, l): (.x: f=l, .y: f=l+64),
// each word packing (split1 lo, split2 hi) -> enc loads ONE dwordx2 per atom.
__global__ __launch_bounds__(256) void combo_kernel(
    const float* __restrict__ W1, const float* __restrict__ W2,
    const float* __restrict__ Wf, const float* __restrict__ bf,
    const float* __restrict__ h, const float* __restrict__ b1,
    const float* __restrict__ b2,
    unsigned int* __restrict__ Tq, unsigned int* __restrict__ phiQ2, int BNA) {
  const int bid = blockIdx.x;
  const int tid = threadIdx.x;

  if (bid < NPTS) {
    // ---- table build (256 threads: f = tid&127, k-half = tid>>7) ----
    __shared__ float g[128];
    __shared__ float part[2][128][2];
    const int pt = bid;
    const int f = tid & 127;
    const int kh = tid >> 7;
    if (tid < 128) {
      const float dpt = pt * TDLT;
      const float o = tid * (5.0f / 127.0f);
      const float dd = dpt - o;
      g[tid] = expf(-dd * dd);
    }
    __syncthreads();
    float s0 = 0.f, s1 = 0.f;
#pragma unroll 8
    for (int kk = 0; kk < 64; ++kk) {
      const int k = kh * 64 + kk;
      s0 = fmaf(g[k], Wf[(size_t)k * 384 + 3 * f + 1], s0);
      s1 = fmaf(g[k], Wf[(size_t)k * 384 + 3 * f + 2], s1);
    }
    part[kh][f][0] = s0;
    part[kh][f][1] = s1;
    __syncthreads();
    if (tid < 128) {
      const float v0 = part[0][tid][0] + part[1][tid][0] + bf[3 * tid + 1];
      const float v1 = part[0][tid][1] + part[1][tid][1] + bf[3 * tid + 2];
      const unsigned int word = f2bf(v0) | ((unsigned int)f2bf(v1) << 16);
      Tq[((size_t)pt * 64 + (tid & 63)) * 2 + (tid >> 6)] = word;
    }
    return;
  }

  // ---- phi block (16 rows), weights packed inline ----
  __shared__ __bf16 hA[4 * 64 * 8];           // 4 KB: h tile, A-frag layout
  __shared__ unsigned short tS[16 * 128];     // 4 KB: t tile, swizzled
  const int lane = tid & 63;
  const int w = tid >> 6;       // 0..3
  const int hw = lane >> 4, lcol = lane & 15;
  const int r0 = (bid - NPTS) * 16;

  // stage h -> A-frag bf16
  {
    const int gl = tid & 63;
    const int kt = tid >> 6;
    const int row = gl & 15;
    const int k0 = kt * 32 + ((gl >> 4) << 3);
    const int gr = r0 + row;
    bf16x8 v;
    if (gr < BNA) {
      const float4 f0 = *(const float4*)&h[(size_t)gr * FDIM + k0];
      const float4 f1 = *(const float4*)&h[(size_t)gr * FDIM + k0 + 4];
      v[0] = (__bf16)f0.x; v[1] = (__bf16)f0.y; v[2] = (__bf16)f0.z; v[3] = (__bf16)f0.w;
      v[4] = (__bf16)f1.x; v[5] = (__bf16)f1.y; v[6] = (__bf16)f1.z; v[7] = (__bf16)f1.w;
    } else {
#pragma unroll
      for (int j = 0; j < 8; ++j) v[j] = (__bf16)0.0f;
    }
    *reinterpret_cast<bf16x8*>(&hA[tid * 8]) = v;
  }

  // pass1 B-frags (W1, inline pack): wave w -> f-cols [w*32, w*32+32)
  bf16x8 B1[2][4];
#pragma unroll
  for (int ftl = 0; ftl < 2; ++ftl) {
    const int col = w * 32 + ftl * 16 + lcol;
#pragma unroll
    for (int kt = 0; kt < 4; ++kt)
#pragma unroll
      for (int j = 0; j < 8; ++j)
        B1[ftl][kt][j] = (__bf16)W1[(size_t)(kt * 32 + hw * 8 + j) * FDIM + col];
  }
  float b1v[2];
#pragma unroll
  for (int ftl = 0; ftl < 2; ++ftl) b1v[ftl] = b1[w * 32 + ftl * 16 + lcol];
  __syncthreads();

  {
    bf16x8 ga[4];
#pragma unroll
    for (int kt = 0; kt < 4; ++kt)
      ga[kt] = *reinterpret_cast<const bf16x8*>(&hA[(kt * 64 + lane) * 8]);
    f32x4 acc[2];
    acc[0] = (f32x4){0.f, 0.f, 0.f, 0.f};
    acc[1] = (f32x4){0.f, 0.f, 0.f, 0.f};
#pragma unroll
    for (int ftl = 0; ftl < 2; ++ftl)
#pragma unroll
      for (int kt = 0; kt < 4; ++kt)
        acc[ftl] = __builtin_amdgcn_mfma_f32_16x16x32_bf16(ga[kt], B1[ftl][kt], acc[ftl], 0, 0, 0);
#pragma unroll
    for (int ftl = 0; ftl < 2; ++ftl)
#pragma unroll
      for (int reg = 0; reg < 4; ++reg) {
        const int row = hw * 4 + reg;
        const int fcol = w * 32 + ftl * 16 + lcol;
        const float x = acc[ftl][reg] + b1v[ftl];
        const float t = x / (1.0f + __expf(-x));
        const int byte = (row * 256 + fcol * 2) ^ ((row & 7) << 4);
        *(unsigned short*)((char*)tS + byte) = f2bf(t);
      }
  }

  // pass2 B-frags (W2 used cols, BOTH splits, inline pack)
  bf16x8 B2[2][2][4];  // [ftl][s][kt]
  float b2v[2][2];
#pragma unroll
  for (int ftl = 0; ftl < 2; ++ftl) {
    const int fcol = w * 32 + ftl * 16 + lcol;
#pragma unroll
    for (int s_ = 0; s_ < 2; ++s_) {
      const int col = 3 * fcol + 1 + s_;
#pragma unroll
      for (int kt = 0; kt < 4; ++kt)
#pragma unroll
        for (int j = 0; j < 8; ++j)
          B2[ftl][s_][kt][j] = (__bf16)W2[(size_t)(kt * 32 + hw * 8 + j) * 384 + col];
      b2v[ftl][s_] = b2[col];
    }
  }
  __syncthreads();

  {
    bf16x8 ta[4];
#pragma unroll
    for (int kt = 0; kt < 4; ++kt) {
      const int row = lcol;
      const int k0 = kt * 32 + hw * 8;
      const int byte = (row * 256 + k0 * 2) ^ ((row & 7) << 4);
      ta[kt] = *reinterpret_cast<const bf16x8*>((const char*)tS + byte);
    }
    f32x4 acc[2][2];
#pragma unroll
    for (int ftl = 0; ftl < 2; ++ftl)
#pragma unroll
      for (int s_ = 0; s_ < 2; ++s_) acc[ftl][s_] = (f32x4){0.f, 0.f, 0.f, 0.f};
#pragma unroll
    for (int ftl = 0; ftl < 2; ++ftl)
#pragma unroll
      for (int s_ = 0; s_ < 2; ++s_)
#pragma unroll
        for (int kt = 0; kt < 4; ++kt)
          acc[ftl][s_] = __builtin_amdgcn_mfma_f32_16x16x32_bf16(ta[kt], B2[ftl][s_][kt],
                                                                 acc[ftl][s_], 0, 0, 0);
#pragma unroll
    for (int ftl = 0; ftl < 2; ++ftl)
#pragma unroll
      for (int reg = 0; reg < 4; ++reg) {
        const int row = hw * 4 + reg;
        const int gr = r0 + row;
        if (gr < BNA) {
          const int fcol = w * 32 + ftl * 16 + lcol;
          const float v0 = acc[ftl][0][reg] + b2v[ftl][0];
          const float v1 = acc[ftl][1][reg] + b2v[ftl][1];
          const unsigned int word = f2bf(v0) | ((unsigned int)f2bf(v1) << 16);
          // interleaved layout: [row][l][hi] with l = fcol&63, hi = fcol>>6
          phiQ2[(size_t)gr * FDIM + (fcol & 63) * 2 + (fcol >> 6)] = word;
        }
      }
  }
}

// ---------------------------------------------------------------------------
// Main kernel (interp): 512 threads = 8 waves, grid (ASPLIT=6, NC, B) = 768
// blocks = exactly 3 blocks/CU resident (launch_bounds(512,6), 32 KB LDS) ->
// 24 waves/CU of TLP. Each wave covers all 256 outputs (lane l -> f=l,
// f=l+64, both splits) for its private atom chunk; per-atom cost cut via
// (a) single dwordx2 phi load (interleaved phiQ2), (b) idx/fr precomputed
// per-lane and broadcast raw. Cross-wave reduction reuses table LDS.
template <int ASPLIT>
__global__ __launch_bounds__(512, 6) void enc_main_kernel(
    const float* __restrict__ xyz, const float* __restrict__ cg_xyz,
    const unsigned int* __restrict__ Tg, const uint2* __restrict__ phiQ2,
    float* __restrict__ pH, float* __restrict__ pV,
    int NA, int NC, int BNC, int BNA) {
  __shared__ uint2 Tl[NPTS * 64];   // 32 KB, [pt][l]; reused as reduction buf

  const int az = blockIdx.x;
  const int c = blockIdx.y;
  const int b = blockIdx.z;
  const int bc = b * NC + c;
  const int tid = threadIdx.x;
  const int l = tid & 63;
  const int wv = tid >> 6;          // 0..7
  const size_t arow = (size_t)b * NA;

  // load table to LDS (exactly 4 uint4 per thread)
  {
    const uint4* src4 = (const uint4*)Tg;
    uint4* dst4 = (uint4*)Tl;
#pragma unroll
    for (int i = 0; i < 4; ++i) dst4[tid + i * 512] = src4[tid + i * 512];
  }

  const float cgx = cg_xyz[bc * 3 + 0];
  const float cgy = cg_xyz[bc * 3 + 1];
  const float cgz = cg_xyz[bc * 3 + 2];

  // atom chunk for this (az, wave)
  const int APA = (NA + ASPLIT - 1) / ASPLIT;
  const int a0 = az * APA;
  const int a_end = min(NA, a0 + APA);
  const int cnt = (a_end > a0) ? (a_end - a0) : 0;
  const int wcnt = (cnt + 7) >> 3;
  const int aw0 = a0 + wv * wcnt;
  const int aw1 = min(a_end, aw0 + wcnt);

  __syncthreads();  // table ready

  float accH0 = 0.f, accH1 = 0.f;
  float accV0[3] = {0.f, 0.f, 0.f};
  float accV1[3] = {0.f, 0.f, 0.f};

  for (int base = aw0; base < aw1; base += 64) {
    int n = aw1 - base;
    if (n > 64) n = 64;

    // batch phase: lane computes its atom's table idx/frac + unit vector
    int idxl = 0;
    float frl = 0.f, ux = 0.f, uy = 0.f, uz = 0.f;
    if (l < n) {
      const int a = base + l;
      const float dx = xyz[(arow + a) * 3 + 0] - cgx;
      const float dy = xyz[(arow + a) * 3 + 1] - cgy;
      const float dz = xyz[(arow + a) * 3 + 2] - cgz;
      const float d = sqrtf(dx * dx + dy * dy + dz * dz);
      const float inv = 1.0f / d;
      ux = dx * inv; uy = dy * inv; uz = dz * inv;
      const float sf = fminf(d * INVTDLT, CLAMPF);
      idxl = (int)sf;
      frl = sf - (float)idxl;
    }

    const uint2* pq2 = phiQ2 + ((size_t)(arow + base)) * 64 + l;

    for (int jb = 0; jb < n; jb += 4) {
      // ---- issue stage: 4 atoms' table reads + phi loads together ----
      uint2 t0[4], t1[4], pv[4];
      float fr[4], sux[4], suy[4], suz[4];
#pragma unroll
      for (int q = 0; q < 4; ++q) {
        const int jj = jb + q;               // wave-uniform
        const int jl = jj & 63;
        const int idx = __builtin_amdgcn_readlane(idxl, jl);
        fr[q] = rdlane(frl, jl);
        t0[q] = Tl[idx * 64 + l];
        t1[q] = Tl[idx * 64 + 64 + l];
        sux[q] = rdlane(ux, jl);
        suy[q] = rdlane(uy, jl);
        suz[q] = rdlane(uz, jl);
        if (jj < n) {
          pv[q] = pq2[(size_t)jj * 64];
        } else {
          pv[q].x = 0u; pv[q].y = 0u;        // zero phi -> zero contribution
        }
      }
      // ---- consume stage: 4 atoms ----
#pragma unroll
      for (int q = 0; q < 4; ++q) {
        const float A1 = bfw_lo(t0[q].x), A2 = bfw_hi(t0[q].x);
        const float B1 = bfw_lo(t1[q].x), B2 = bfw_hi(t1[q].x);
        const float C1 = bfw_lo(t0[q].y), C2 = bfw_hi(t0[q].y);
        const float D1 = bfw_lo(t1[q].y), D2 = bfw_hi(t1[q].y);
        const float S1a = fmaf(fr[q], B1 - A1, A1);  // split1, f=l
        const float S2a = fmaf(fr[q], B2 - A2, A2);  // split2, f=l
        const float S1b = fmaf(fr[q], D1 - C1, C1);  // split1, f=l+64
        const float S2b = fmaf(fr[q], D2 - C2, C2);  // split2, f=l+64

        const float p1a = bfw_lo(pv[q].x), p2a = bfw_hi(pv[q].x);
        const float p1b = bfw_lo(pv[q].y), p2b = bfw_hi(pv[q].y);

        accH0 = fmaf(S1a, p1a, accH0);
        accH1 = fmaf(S1b, p1b, accH1);
        const float t2a = S2a * p2a;
        const float t2b = S2b * p2b;
        accV0[0] = fmaf(t2a, sux[q], accV0[0]);
        accV0[1] = fmaf(t2a, suy[q], accV0[1]);
        accV0[2] = fmaf(t2a, suz[q], accV0[2]);
        accV1[0] = fmaf(t2b, sux[q], accV1[0]);
        accV1[1] = fmaf(t2b, suy[q], accV1[1]);
        accV1[2] = fmaf(t2b, suz[q], accV1[2]);
      }
    }
  }

  // ---- cross-wave reduction, reusing table LDS (red[comp][wv][l]) ----
  __syncthreads();  // everyone done reading the table
  float* red = (float*)Tl;
  red[0 * 512 + wv * 64 + l] = accH0;
  red[1 * 512 + wv * 64 + l] = accH1;
  red[2 * 512 + wv * 64 + l] = accV0[0];
  red[3 * 512 + wv * 64 + l] = accV0[1];
  red[4 * 512 + wv * 64 + l] = accV0[2];
  red[5 * 512 + wv * 64 + l] = accV1[0];
  red[6 * 512 + wv * 64 + l] = accV1[1];
  red[7 * 512 + wv * 64 + l] = accV1[2];
  __syncthreads();
  {
    const int comp = tid >> 6;   // 0..7
    const int sl = tid & 63;
    float v = 0.f;
#pragma unroll
    for (int w8 = 0; w8 < 8; ++w8) v += red[comp * 512 + w8 * 64 + sl];
    if (comp == 0) {
      pH[((size_t)az * BNC + bc) * FDIM + sl] = v;
    } else if (comp == 1) {
      pH[((size_t)az * BNC + bc) * FDIM + sl + 64] = v;
    } else if (comp < 5) {
      pV[(((size_t)az * BNC + bc) * FDIM + sl) * 3 + (comp - 2)] = v;
    } else {
      pV[(((size_t)az * BNC + bc) * FDIM + sl + 64) * 3 + (comp - 5)] = v;
    }
  }
}

// ---------------------------------------------------------------------------
template <int P>
__global__ __launch_bounds__(FDIM) void reduce_kernel(
    const float* __restrict__ H, const float* __restrict__ pH, const float* __restrict__ pV,
    float* __restrict__ out, int BNC) {
  const int bc = blockIdx.x;
  const int f = threadIdx.x;
  float s = H[(size_t)bc * FDIM + f];
#pragma unroll
  for (int p = 0; p < P; ++p) s += pH[((size_t)p * BNC + bc) * FDIM + f];
  out[(size_t)bc * FDIM + f] = s;
  float* outV = out + (size_t)BNC * FDIM;
#pragma unroll
  for (int x = 0; x < 3; ++x) {
    float v = 0.f;
#pragma unroll
    for (int p = 0; p < P; ++p) v += pV[(((size_t)p * BNC + bc) * FDIM + f) * 3 + x];
    outV[((size_t)bc * FDIM + f) * 3 + x] = v;
  }
}

extern "C" void kernel_launch(void* const* d_in, const int* in_sizes, int n_in,
                              void* d_out, int out_size, void* d_ws, size_t ws_size,
                              hipStream_t stream) {
  // inputs: 0 assign(unused), 1 h, 2 H, 3 cg_xyz, 4 xyz, 5 cg_adj(unused),
  //         6 Wf, 7 bf, 8 W1, 9 b1, 10 W2, 11 b2
  const float* h      = (const float*)d_in[1];
  const float* Hc     = (const float*)d_in[2];
  const float* cg_xyz = (const float*)d_in[3];
  const float* xyz    = (const float*)d_in[4];
  const float* Wf     = (const float*)d_in[6];
  const float* bf     = (const float*)d_in[7];
  const float* W1     = (const float*)d_in[8];
  const float* b1     = (const float*)d_in[9];
  const float* W2     = (const float*)d_in[10];
  const float* b2     = (const float*)d_in[11];

  const int BNC = in_sizes[2] / FDIM;      // B*NC
  const int NC  = in_sizes[5] / BNC;       // cg_adj = B*NC*NC
  const int B   = BNC / NC;
  const int NA  = in_sizes[0] / B;
  const int BNA = B * NA;
  constexpr int ASPLIT = 6;                // 768 blocks = 3/CU, P = 6

  // Workspace: Tq (32 KB) + phiQ2 (BNA*128 u32) + pH + pV
  char* wsb = (char*)d_ws;
  unsigned int* Tq    = (unsigned int*)wsb;                         // 32768 B
  unsigned int* phiQ2 = (unsigned int*)(wsb + 32768);
  char* pp = wsb + 32768 + (size_t)BNA * FDIM * 4;
  float* pH = (float*)pp;                  pp += (size_t)ASPLIT * BNC * FDIM * 4;
  float* pV = (float*)pp;

  const int nphi = (BNA + 15) / 16;
  combo_kernel<<<NPTS + nphi, 256, 0, stream>>>(W1, W2, Wf, bf, h, b1, b2,
                                                Tq, phiQ2, BNA);
  enc_main_kernel<ASPLIT><<<dim3(ASPLIT, NC, B), 512, 0, stream>>>(
      xyz, cg_xyz, Tq, (const uint2*)phiQ2, pH, pV, NA, NC, BNC, BNA);
  reduce_kernel<ASPLIT><<<BNC, FDIM, 0, stream>>>(Hc, pH, pV, (float*)d_out, BNC);
}